// Round 9
// baseline (3127.205 us; speedup 1.0000x reference)
//
#include <hip/hip_runtime.h>
#include <hip/hip_bf16.h>
#include <math.h>

#define BATCH 4096
#define HID 256
#define OUT_W 15

typedef unsigned short ushort_t;
typedef unsigned int uint_t;

using bf16x8 = __attribute__((ext_vector_type(8))) short;
using f32x4v = __attribute__((ext_vector_type(4))) float;

__device__ __forceinline__ float sigf(float x) { return 1.0f / (1.0f + __expf(-x)); }
__device__ __forceinline__ float tanh_fast(float x) { return 1.0f - 2.0f / (__expf(2.0f * x) + 1.0f); }
__device__ __forceinline__ float bf2f(ushort_t u) { return __uint_as_float(((uint_t)u) << 16); }
__device__ __forceinline__ ushort_t f2bf(float x) {
    uint_t b = __float_as_uint(x);
    return (ushort_t)((b + 0x7fffu + ((b >> 16) & 1u)) >> 16);
}

// ---------------------------------------------------------------------------
// Prep. Blocks: 0 bias_all, 1 samp tables, 2 mlp transposes, 3 conv packs,
// 4..11 Wb (W_hh bf16), 12..19 Wobs_b (W_ih cols 0..399 -> bf16 [n][416]),
// 20 WsampT.
// ---------------------------------------------------------------------------
__global__ __launch_bounds__(256) void prep_kernel(
    const float* __restrict__ W_ih, const float* __restrict__ W_hh,
    const float* __restrict__ b_ih, const float* __restrict__ b_hh,
    const float* __restrict__ addr_emb, const float* __restrict__ pid_emb,
    const float* __restrict__ sid_emb,
    const float* __restrict__ mlp_w2, const float* __restrict__ mlp_w3,
    const float* __restrict__ conv1_w, const float* __restrict__ conv1_b,
    const float* __restrict__ conv2_w,
    ushort_t* __restrict__ Wb, ushort_t* __restrict__ Wobs_b,
    float* __restrict__ WsampT,
    float* __restrict__ bias_all, float* __restrict__ pid_rows,
    float* __restrict__ sid_rows, float* __restrict__ w2t, float* __restrict__ w3t,
    float* __restrict__ w1p, ushort_t* __restrict__ Btg)
{
    int blk = blockIdx.x, t = threadIdx.x;
    if (blk == 0) {
        const int aids[7] = {0, 1, 4, 2, 3, 5, 6};
        for (int s = 0; s < 7; s++) {
            int aid = aids[s];
            for (int j = t; j < 1024; j += 256) {
                float v = b_ih[j] + b_hh[j];
                #pragma unroll
                for (int k = 0; k < 16; k++)
                    v += addr_emb[aid * 16 + k] * W_ih[(size_t)j * 432 + 416 + k];
                bias_all[s * 1024 + j] = v;
            }
        }
    } else if (blk == 1) {
        for (int p = 0; p < 3; p++)
            for (int j = t; j < 1024; j += 256) {
                float v = 0.f;
                #pragma unroll
                for (int k = 0; k < 16; k++)
                    v += pid_emb[p * 16 + k] * W_ih[(size_t)j * 432 + 400 + k];
                pid_rows[p * 1024 + j] = v;
            }
        for (int p = 0; p < 2; p++)
            for (int j = t; j < 1024; j += 256) {
                float v = 0.f;
                #pragma unroll
                for (int k = 0; k < 16; k++)
                    v += sid_emb[p * 16 + k] * W_ih[(size_t)j * 432 + 400 + k];
                sid_rows[p * 1024 + j] = v;
            }
    } else if (blk == 2) {
        for (int i = t; i < 10000; i += 256) {
            int o = i / 100, k = i % 100;
            w2t[k * 100 + o] = mlp_w2[i];
        }
        for (int i = t; i < 1600; i += 256) {
            int o = i / 100, k = i % 100;
            w3t[k * 16 + o] = mlp_w3[i];
        }
    } else if (blk == 3) {
        for (int i = t; i < 384; i += 256) {
            int ic = i / 12, k = i % 12;
            float v = 0.f;
            if (k < 9) v = conv1_w[ic * 9 + k];
            else if (k == 9) v = conv1_b[ic];
            w1p[i] = v;
        }
        // Btg[(tap*16 + oc)*32 + ic] = conv2_w[(oc*32+ic)*9 + tap]
        for (int i = t; i < 4608; i += 256) {
            int tap = i >> 9;
            int rem = i & 511;
            int oc = rem >> 5, ic = rem & 31;
            Btg[i] = f2bf(conv2_w[(size_t)(oc * 32 + ic) * 9 + tap]);
        }
    } else if (blk < 12) {
        int seg = blk - 4;  // W_hh (1024x256) -> bf16 [n][k]
        for (int i = seg * 32768 + t; i < (seg + 1) * 32768; i += 256)
            Wb[i] = f2bf(W_hh[i]);
    } else if (blk < 20) {
        int seg = blk - 12;  // Wobs_b (1024 x 416): 425984 total / 8 = 53248
        for (int i = seg * 53248 + t; i < (seg + 1) * 53248; i += 256) {
            int n = i / 416, k = i % 416;
            Wobs_b[i] = (k < 400) ? f2bf(W_ih[(size_t)n * 432 + k]) : (ushort_t)0;
        }
    } else {
        // WsampT[k*1024 + j] = W_ih[j*432 + 400 + k]
        for (int i = t; i < 16384; i += 256) {
            int k = i >> 10, j = i & 1023;
            WsampT[i] = W_ih[(size_t)j * 432 + 400 + k];
        }
    }
}

// ---------------------------------------------------------------------------
// Conv encoder v3: conv1 reads obs straight from global (L1-cached, float4,
// boundary predication). c1 in a 17-row two-phase ring buffer (bf16,
// even/odd column split, pos stride 40 ush = conflict-free b128 reads).
// conv2 = 9 tap-shifted MFMA GEMMs, Cacc persists across phases.
// LDS = 46.4 KB -> 3 blocks/CU.
// ---------------------------------------------------------------------------
#define CE_RS 640   // 16 even positions * 40 ushorts
#define CO_RS 680   // 17 odd positions * 40 ushorts
__global__ __launch_bounds__(256, 3) void conv_kernel(
    const float* __restrict__ obs, const float* __restrict__ w1p,
    const ushort_t* __restrict__ Btg, const float* __restrict__ b2,
    ushort_t* __restrict__ obs_emb_b)
{
    __shared__ __align__(16) ushort_t cE[17 * CE_RS];  // 21760 B
    __shared__ __align__(16) ushort_t cO[17 * CO_RS];  // 23120 B
    __shared__ __align__(16) float w1s[384];           // 1536 B
    const int b = blockIdx.x, t = threadIdx.x;
    const float4* og4 = (const float4*)(obs + (size_t)b * 4096);  // [64][16]

    if (t < 96) ((float4*)w1s)[t] = ((const float4*)w1p)[t];
    // zero cO position 0 (c1 col -1): FULL 40 ushorts (20 uints) x 17 rows
    {
        uint_t* zO = (uint_t*)cO;
        for (int i = t; i < 340; i += 256) {
            int row = i / 20, d = i % 20;
            zO[row * (CO_RS / 2) + d] = 0;
        }
    }

    const int w = t >> 6, L = t & 63, q = L >> 4, ln = L & 15;
    bf16x8 Bv[9];
    #pragma unroll
    for (int tap = 0; tap < 9; tap++)
        Bv[tap] = *reinterpret_cast<const bf16x8*>(&Btg[(tap * 16 + ln) * 32 + q * 8]);

    f32x4v Cacc[4];
    #pragma unroll
    for (int i = 0; i < 4; i++) Cacc[i] = f32x4v{0.f, 0.f, 0.f, 0.f};
    __syncthreads();  // w1s + cO zeros visible

    for (int hf = 0; hf < 2; hf++) {
        if (hf) __syncthreads();  // phase-0 MFMA reads done before overwrite
        // conv1: 272 tasks = 17 buf rows x 16 col-pairs
        for (int iter = 0; iter < 2; iter++) {
            int task = t + iter * 256;
            if (task < 272) {
                int j = task >> 4;       // buffer row 0..16
                int G = task & 15;       // cols 2G, 2G+1
                int r = 16 * hf - 1 + j; // c1 row (-1..31)
                float msk = (r >= 0) ? 1.f : 0.f;
                // obs rows 2r-1..2r+1, cols 4G-4..4G+3 (2 float4/row)
                float Pt[3][8];
                #pragma unroll
                for (int d = 0; d < 3; d++) {
                    int orow = 2 * r - 1 + d;
                    bool rok = (orow >= 0) && (orow <= 63);
                    float4 A = (rok && G > 0) ? og4[orow * 16 + G - 1]
                                              : float4{0.f, 0.f, 0.f, 0.f};
                    float4 Bq = rok ? og4[orow * 16 + G] : float4{0.f, 0.f, 0.f, 0.f};
                    Pt[d][0] = A.x; Pt[d][1] = A.y; Pt[d][2] = A.z; Pt[d][3] = A.w;
                    Pt[d][4] = Bq.x; Pt[d][5] = Bq.y; Pt[d][6] = Bq.z; Pt[d][7] = Bq.w;
                }
                for (int round = 0; round < 4; round++) {
                    uint_t pk[2][4];
                    #pragma unroll
                    for (int icl = 0; icl < 8; icl++) {
                        int ic = round * 8 + icl;
                        const float* qw = &w1s[ic * 12];
                        float4 qa = *(const float4*)qw;
                        float4 qb = *(const float4*)(qw + 4);
                        float w8 = qw[8], bb = qw[9];
                        float wv[9] = {qa.x, qa.y, qa.z, qa.w,
                                       qb.x, qb.y, qb.z, qb.w, w8};
                        #pragma unroll
                        for (int cc = 0; cc < 2; cc++) {
                            float s = bb;
                            #pragma unroll
                            for (int d = 0; d < 3; d++)
                                #pragma unroll
                                for (int dx = 0; dx < 3; dx++)
                                    s += wv[d * 3 + dx] * Pt[d][2 * cc + 3 + dx];
                            s = fmaxf(s, 0.f) * msk;
                            ushort_t u = f2bf(s);
                            if (icl & 1) pk[cc][icl >> 1] |= ((uint_t)u) << 16;
                            else         pk[cc][icl >> 1] = u;
                        }
                    }
                    *(uint4*)&cE[j * CE_RS + G * 40 + round * 8] =
                        uint4{pk[0][0], pk[0][1], pk[0][2], pk[0][3]};
                    *(uint4*)&cO[j * CO_RS + (G + 1) * 40 + round * 8] =
                        uint4{pk[1][0], pk[1][1], pk[1][2], pk[1][3]};
                }
            }
        }
        __syncthreads();
        // conv2 MFMA: wave w (0..3) handles y = 8hf + 2w + i
        #pragma unroll
        for (int i = 0; i < 2; i++) {
            int ci = hf * 2 + i;
            #pragma unroll
            for (int dy = 0; dy < 3; dy++) {
                int jr = 4 * w + 2 * i + dy;  // buffer row
                bf16x8 a0 = *reinterpret_cast<const bf16x8*>(&cO[jr * CO_RS + ln * 40 + q * 8]);
                bf16x8 a1 = *reinterpret_cast<const bf16x8*>(&cE[jr * CE_RS + ln * 40 + q * 8]);
                bf16x8 a2 = *reinterpret_cast<const bf16x8*>(&cO[jr * CO_RS + (ln + 1) * 40 + q * 8]);
                Cacc[ci] = __builtin_amdgcn_mfma_f32_16x16x32_bf16(a0, Bv[dy * 3 + 0], Cacc[ci], 0, 0, 0);
                Cacc[ci] = __builtin_amdgcn_mfma_f32_16x16x32_bf16(a1, Bv[dy * 3 + 1], Cacc[ci], 0, 0, 0);
                Cacc[ci] = __builtin_amdgcn_mfma_f32_16x16x32_bf16(a2, Bv[dy * 3 + 2], Cacc[ci], 0, 0, 0);
            }
        }
    }
    __syncthreads();

    // epilogue: bias+relu -> c2 overlay on cE (fp32, oc stride 260), pool
    float* c2b = (float*)cE;  // 16*260*4 = 16640 B
    {
        float bb2 = b2[ln];
        #pragma unroll
        for (int ci = 0; ci < 4; ci++) {
            int y = 8 * (ci >> 1) + 2 * w + (ci & 1);
            float4 o;
            o.x = fmaxf(Cacc[ci][0] + bb2, 0.f);
            o.y = fmaxf(Cacc[ci][1] + bb2, 0.f);
            o.z = fmaxf(Cacc[ci][2] + bb2, 0.f);
            o.w = fmaxf(Cacc[ci][3] + bb2, 0.f);
            *(float4*)&c2b[ln * 260 + y * 16 + q * 4] = o;
        }
    }
    __syncthreads();
    for (int p = t; p < 400; p += 256) {
        int c = p / 25, rem = p % 25, py = rem / 5, px = rem % 5;
        float s = 0.f;
        #pragma unroll
        for (int dy = 0; dy < 3; dy++)
            #pragma unroll
            for (int dx = 0; dx < 3; dx++)
                s += c2b[c * 260 + (3 * py + dy) * 16 + 3 * px + dx];
        obs_emb_b[(size_t)b * 416 + p] = f2bf(s * (1.f / 9.f));
    }
    if (t < 16) obs_emb_b[(size_t)b * 416 + 400 + t] = 0;
}

// ---------------------------------------------------------------------------
// obs_part (bf16) = obs_emb_b (B x 416 bf16) @ Wobs_b.T -> (B x 1024), MFMA.
// ---------------------------------------------------------------------------
__global__ __launch_bounds__(512, 2) void obs_gemm(
    const ushort_t* __restrict__ Ab, const ushort_t* __restrict__ Wob,
    ushort_t* __restrict__ outp)
{
    __shared__ __align__(16) ushort_t As[64 * 424];  // 54272 B (424 = pad)
    const int t = threadIdx.x;
    const int bm = blockIdx.x & 63, bn = blockIdx.x >> 6;
    const int b0 = bm * 64;

    #pragma unroll
    for (int i = 0; i < 7; i++) {
        int idx = t + i * 512;
        if (idx < 3328) {  // 64 rows x 52 float4
            int row = idx / 52, c = idx % 52;
            float4 v = ((const float4*)(Ab + (size_t)(b0 + row) * 416))[c];
            *(float4*)&As[row * 424 + c * 8] = v;
        }
    }
    __syncthreads();

    const int w = t >> 6, L = t & 63, q = L >> 4, ln = L & 15;
    const int m0 = (w & 3) * 16;
    const int ncol0 = bn * 128 + (w >> 2) * 64;

    bf16x8 a[13];
    #pragma unroll
    for (int kk = 0; kk < 13; kk++)
        a[kk] = *reinterpret_cast<const bf16x8*>(&As[(m0 + ln) * 424 + kk * 32 + q * 8]);

    #pragma unroll
    for (int nt = 0; nt < 4; nt++) {
        int ncol = ncol0 + nt * 16 + ln;
        const ushort_t* wr = Wob + (size_t)ncol * 416 + q * 8;
        f32x4v z = {0.f, 0.f, 0.f, 0.f};
        #pragma unroll
        for (int kk = 0; kk < 13; kk++) {
            bf16x8 bv = *reinterpret_cast<const bf16x8*>(wr + kk * 32);
            z = __builtin_amdgcn_mfma_f32_16x16x32_bf16(a[kk], bv, z, 0, 0, 0);
        }
        #pragma unroll
        for (int r = 0; r < 4; r++)
            outp[(size_t)(b0 + m0 + q * 4 + r) * 1024 + ncol] = f2bf(z[r]);
    }
}

// ---------------------------------------------------------------------------
// step0 elementwise: h=c=0 -> c0 (fp32), hb0 (bf16)
// ---------------------------------------------------------------------------
__global__ __launch_bounds__(256) void step0_ew(
    const ushort_t* __restrict__ obs_part, const float* __restrict__ bias_s,
    float* __restrict__ c_out, ushort_t* __restrict__ hb_out)
{
    const int R = blockIdx.x, u = threadIdx.x;
    float pre[4];
    #pragma unroll
    for (int g = 0; g < 4; g++)
        pre[g] = bf2f(obs_part[(size_t)R * 1024 + g * 256 + u]) + bias_s[g * 256 + u];
    float c2 = sigf(pre[0]) * tanh_fast(pre[2]);
    float hv = sigf(pre[3]) * tanh_fast(c2);
    c_out[(size_t)R * 256 + u] = c2;
    hb_out[(size_t)R * 256 + u] = f2bf(hv);
}

// ---------------------------------------------------------------------------
// Unified MFMA LSTM step. NSUB=2: two independent sets batched over a
// doubled grid. DUAL: one GEMM, two bias-epilogues (shared c_in).
// ---------------------------------------------------------------------------
template <int SAMP, int HEAD_N, int NSUB, bool DUAL>
__global__ __launch_bounds__(512, 4) void lstm_mfma(
    const ushort_t* __restrict__ hb_in0, const ushort_t* __restrict__ hb_in1,
    const float* __restrict__ c_in0, const float* __restrict__ c_in1,
    ushort_t* __restrict__ hb_out0, ushort_t* __restrict__ hb_out1,
    float* __restrict__ c_out0, float* __restrict__ c_out1,
    ushort_t* __restrict__ hb_out_b, float* __restrict__ c_out_b,
    const ushort_t* __restrict__ obs_part,
    const float* __restrict__ bias0, const float* __restrict__ bias1,
    const float* __restrict__ bias_b,
    const float* __restrict__ samp_rows,
    const int* __restrict__ sidx0, const int* __restrict__ sidx1,
    const float* __restrict__ rp0_emb, const float* __restrict__ WsampT,
    const ushort_t* __restrict__ Wb,
    const float* __restrict__ head_w, const float* __restrict__ head_b,
    float* __restrict__ out, int off0, int off1)
{
    __shared__ ushort_t hAs[64 * 264];   // 33792 B
    __shared__ float hws[3 * 256];
    __shared__ float red[64 * 8 * 3];
    const int t = threadIdx.x;
    int blk = blockIdx.x;
    const int sub = (NSUB == 2) ? (blk >> 9) : 0;
    blk &= 511;
    const int bm = blk & 63, bu = blk >> 6;
    const int b0 = bm * 64;

    const ushort_t* hb_in = sub ? hb_in1 : hb_in0;
    const float* c_in = sub ? c_in1 : c_in0;
    ushort_t* hb_out = sub ? hb_out1 : hb_out0;
    float* c_out = sub ? c_out1 : c_out0;
    const float* bias_s = sub ? bias1 : bias0;
    const int* samp_idx = sub ? sidx1 : sidx0;
    const int out_off = sub ? off1 : off0;

    #pragma unroll
    for (int i = 0; i < 4; i++) {
        int idx = t + i * 512, row = idx >> 5, c = idx & 31;
        float4 v = reinterpret_cast<const float4*>(hb_in + (size_t)(b0 + row) * 256)[c];
        *reinterpret_cast<float4*>(&hAs[row * 264 + c * 8]) = v;
    }
    if (HEAD_N > 0 && bu == 0)
        for (int i = t; i < HEAD_N * 256; i += 512) hws[i] = head_w[i];
    __syncthreads();

    const int w = t >> 6, L = t & 63, q = L >> 4, ln = L & 15;
    const int m0 = (w & 3) * 16;
    const int unit = bu * 32 + (w >> 2) * 16 + ln;

    bf16x8 a[8];
    #pragma unroll
    for (int kk = 0; kk < 8; kk++)
        a[kk] = *reinterpret_cast<const bf16x8*>(&hAs[(m0 + ln) * 264 + kk * 32 + q * 8]);

    f32x4v acc[4];
    #pragma unroll
    for (int g = 0; g < 4; g++) {
        f32x4v z = {0.f, 0.f, 0.f, 0.f};
        const ushort_t* wrow = Wb + (size_t)(g * 256 + unit) * 256 + q * 8;
        #pragma unroll
        for (int kk = 0; kk < 8; kk++) {
            bf16x8 bv = *reinterpret_cast<const bf16x8*>(wrow + kk * 32);
            z = __builtin_amdgcn_mfma_f32_16x16x32_bf16(a[kk], bv, z, 0, 0, 0);
        }
        acc[g] = z;
    }

    #pragma unroll
    for (int r = 0; r < 4; r++) {
        const int R = b0 + m0 + q * 4 + r;
        float base[4];
        #pragma unroll
        for (int g = 0; g < 4; g++)
            base[g] = acc[g][r] + bf2f(obs_part[(size_t)R * 1024 + g * 256 + unit]);
        if (SAMP == 1) {
            int si = samp_idx[R];
            #pragma unroll
            for (int g = 0; g < 4; g++) base[g] += samp_rows[si * 1024 + g * 256 + unit];
        }
        if (SAMP == 2) {
            #pragma unroll
            for (int k = 0; k < 16; k++) {
                float e = rp0_emb[(size_t)R * 16 + k];
                #pragma unroll
                for (int g = 0; g < 4; g++) base[g] += e * WsampT[k * 1024 + g * 256 + unit];
            }
        }
        float ci = c_in[(size_t)R * 256 + unit];
        {
            float pi = base[0] + bias_s[unit];
            float pf = base[1] + bias_s[256 + unit];
            float pg = base[2] + bias_s[512 + unit];
            float po = base[3] + bias_s[768 + unit];
            float c2 = sigf(pf) * ci + sigf(pi) * tanh_fast(pg);
            float hv = sigf(po) * tanh_fast(c2);
            c_out[(size_t)R * 256 + unit] = c2;
            hb_out[(size_t)R * 256 + unit] = f2bf(hv);
        }
        if (DUAL) {
            float pi = base[0] + bias_b[unit];
            float pf = base[1] + bias_b[256 + unit];
            float pg = base[2] + bias_b[512 + unit];
            float po = base[3] + bias_b[768 + unit];
            float c2 = sigf(pf) * ci + sigf(pi) * tanh_fast(pg);
            float hv = sigf(po) * tanh_fast(c2);
            c_out_b[(size_t)R * 256 + unit] = c2;
            hb_out_b[(size_t)R * 256 + unit] = f2bf(hv);
        }
    }

    if (HEAD_N > 0 && bu == 0) {
        const int row = t >> 3, seg = t & 7;
        float part[3] = {0.f, 0.f, 0.f};
        #pragma unroll
        for (int j = 0; j < 4; j++) {
            uint4 v = *reinterpret_cast<const uint4*>(&hAs[row * 264 + seg * 32 + j * 8]);
            uint_t dw[4] = {v.x, v.y, v.z, v.w};
            #pragma unroll
            for (int d = 0; d < 4; d++) {
                float f0 = __uint_as_float(dw[d] << 16);
                float f1 = __uint_as_float(dw[d] & 0xffff0000u);
                int k = seg * 32 + j * 8 + d * 2;
                #pragma unroll
                for (int n = 0; n < HEAD_N; n++)
                    part[n] += f0 * hws[n * 256 + k] + f1 * hws[n * 256 + k + 1];
            }
        }
        #pragma unroll
        for (int n = 0; n < HEAD_N; n++) red[(row * 8 + seg) * 3 + n] = part[n];
        __syncthreads();
        if (t < 64) {
            #pragma unroll
            for (int n = 0; n < HEAD_N; n++) {
                float s = head_b[n];
                #pragma unroll
                for (int p = 0; p < 8; p++) s += red[(t * 8 + p) * 3 + n];
                out[(size_t)(b0 + t) * OUT_W + out_off + n] = s;
            }
        }
    }
}

// ---------------------------------------------------------------------------
// rp head: out[:, off:off+2] = rp[:, :2] + exp(rp[:, 2:]) * eps, from hb.
// ---------------------------------------------------------------------------
__global__ __launch_bounds__(256) void rp_head(
    const ushort_t* __restrict__ hb, const float* __restrict__ head_w,
    const float* __restrict__ head_b, const float* __restrict__ eps,
    float* __restrict__ out, int out_off, float* __restrict__ rp_store)
{
    __shared__ float hw[1024];
    __shared__ float red[64 * 4 * 4];
    const int t = threadIdx.x;
    const int b0 = blockIdx.x * 64;
    for (int i = t; i < 1024; i += 256) hw[i] = head_w[i];
    __syncthreads();
    const int r = t >> 2, p = t & 3;
    {
        const int R = b0 + r;
        float part[4] = {0.f, 0.f, 0.f, 0.f};
        const ushort_t* hr = hb + (size_t)R * 256 + p * 64;
        #pragma unroll
        for (int j = 0; j < 8; j++) {
            uint4 v = *reinterpret_cast<const uint4*>(hr + j * 8);
            uint_t dw[4] = {v.x, v.y, v.z, v.w};
            #pragma unroll
            for (int d = 0; d < 4; d++) {
                float f0 = __uint_as_float(dw[d] << 16);
                float f1 = __uint_as_float(dw[d] & 0xffff0000u);
                int k = p * 64 + j * 8 + d * 2;
                #pragma unroll
                for (int n = 0; n < 4; n++)
                    part[n] += f0 * hw[n * 256 + k] + f1 * hw[n * 256 + k + 1];
            }
        }
        #pragma unroll
        for (int n = 0; n < 4; n++) red[(r * 4 + p) * 4 + n] = part[n];
    }
    __syncthreads();
    if (t < 64) {
        const int R = b0 + t;
        float s[4];
        #pragma unroll
        for (int n = 0; n < 4; n++) {
            float v = head_b[n];
            #pragma unroll
            for (int p2 = 0; p2 < 4; p2++) v += red[(t * 4 + p2) * 4 + n];
            s[n] = v;
        }
        float v0 = s[0] + __expf(s[2]) * eps[(size_t)R * 2 + 0];
        float v1 = s[1] + __expf(s[3]) * eps[(size_t)R * 2 + 1];
        out[(size_t)R * OUT_W + out_off + 0] = v0;
        out[(size_t)R * OUT_W + out_off + 1] = v1;
        if (rp_store) {
            rp_store[(size_t)R * 2 + 0] = v0;
            rp_store[(size_t)R * 2 + 1] = v1;
        }
    }
}

// ---------------------------------------------------------------------------
// MLP: rp0 (B x 2) -> 100 -> 100 -> rp0_emb (B x 16)
// ---------------------------------------------------------------------------
__global__ __launch_bounds__(128) void mlp_kernel(
    const float* __restrict__ rp0, const float* __restrict__ w1,
    const float* __restrict__ b1, const float* __restrict__ w2t,
    const float* __restrict__ b2, const float* __restrict__ w3t,
    const float* __restrict__ b3, float* __restrict__ emb)
{
    __shared__ float z1[100], z2[100];
    int row = blockIdx.x, t = threadIdx.x;
    float r0 = rp0[(size_t)row * 2], r1 = rp0[(size_t)row * 2 + 1];
    if (t < 100) z1[t] = tanh_fast(b1[t] + w1[t * 2] * r0 + w1[t * 2 + 1] * r1);
    __syncthreads();
    if (t < 100) {
        float s = b2[t];
        for (int k = 0; k < 100; k++) s += w2t[k * 100 + t] * z1[k];
        z2[t] = tanh_fast(s);
    }
    __syncthreads();
    if (t < 16) {
        float s = b3[t];
        for (int k = 0; k < 100; k++) s += w3t[k * 16 + t] * z2[k];
        emb[(size_t)row * 16 + t] = s;
    }
}

// ---------------------------------------------------------------------------
extern "C" void kernel_launch(void* const* d_in, const int* in_sizes, int n_in,
                              void* d_out, int out_size, void* d_ws, size_t ws_size,
                              hipStream_t stream)
{
    const float* obs        = (const float*)d_in[0];
    const int*   program_id = (const int*)d_in[1];
    const int*   shape_id   = (const int*)d_in[2];
    const int*   shape_id_0 = (const int*)d_in[3];
    const int*   shape_id_1 = (const int*)d_in[4];
    const float* eps_rp     = (const float*)d_in[5];
    const float* eps_rp0    = (const float*)d_in[6];
    const float* eps_rp1    = (const float*)d_in[7];
    const float* conv1_w    = (const float*)d_in[8];
    const float* conv1_b    = (const float*)d_in[9];
    const float* conv2_w    = (const float*)d_in[10];
    const float* conv2_b    = (const float*)d_in[11];
    const float* mlp_w1     = (const float*)d_in[12];
    const float* mlp_b1     = (const float*)d_in[13];
    const float* mlp_w2     = (const float*)d_in[14];
    const float* mlp_b2     = (const float*)d_in[15];
    const float* mlp_w3     = (const float*)d_in[16];
    const float* mlp_b3     = (const float*)d_in[17];
    const float* W_ih       = (const float*)d_in[18];
    const float* b_ih       = (const float*)d_in[19];
    const float* W_hh       = (const float*)d_in[20];
    const float* b_hh       = (const float*)d_in[21];
    const float* addr_emb   = (const float*)d_in[22];
    const float* pid_emb    = (const float*)d_in[23];
    const float* sid_emb    = (const float*)d_in[24];
    const float* pid_ext_w  = (const float*)d_in[25];
    const float* pid_ext_b  = (const float*)d_in[26];
    const float* sid_ext_w  = (const float*)d_in[27];
    const float* sid_ext_b  = (const float*)d_in[28];
    const float* rp_ext_w   = (const float*)d_in[29];
    const float* rp_ext_b   = (const float*)d_in[30];
    float* out = (float*)d_out;

    // workspace (float slots)
    float* ws = (float*)d_ws;
    size_t off = 0;
    ushort_t* Wb     = (ushort_t*)(ws + off); off += 131072;             // 1024x256 bf16
    ushort_t* Wobs_b = (ushort_t*)(ws + off); off += 212992;             // 1024x416 bf16
    ushort_t* obs_emb_b = (ushort_t*)(ws + off); off += (size_t)BATCH * 208;  // Bx416 bf16
    ushort_t* obs_part  = (ushort_t*)(ws + off); off += (size_t)BATCH * 512;  // Bx1024 bf16
    ushort_t* hb0 = (ushort_t*)(ws + off); off += (size_t)BATCH * 128;
    ushort_t* hbA = (ushort_t*)(ws + off); off += (size_t)BATCH * 128;
    ushort_t* hbD = (ushort_t*)(ws + off); off += (size_t)BATCH * 128;
    ushort_t* hbE = (ushort_t*)(ws + off); off += (size_t)BATCH * 128;
    ushort_t* hbC = (ushort_t*)(ws + off); off += (size_t)BATCH * 128;
    float* c0 = ws + off; off += (size_t)BATCH * 256;
    float* cA = ws + off; off += (size_t)BATCH * 256;
    float* cB = ws + off; off += (size_t)BATCH * 256;
    float* bias_all = ws + off; off += 7 * 1024;
    float* pid_rows = ws + off; off += 3 * 1024;
    float* sid_rows = ws + off; off += 2 * 1024;
    float* WsampT   = ws + off; off += 16 * 1024;
    float* rp0      = ws + off; off += (size_t)BATCH * 2;
    float* rp0_emb  = ws + off; off += (size_t)BATCH * 16;
    float* w2t = ws + off; off += 10000;
    float* w3t = ws + off; off += 1600;
    float* w1p = ws + off; off += 384;
    ushort_t* Btg = (ushort_t*)(ws + off); off += 2304;
    ushort_t* hbB = hb0;   // alias: hb0 dead after step1
    ushort_t* hbF = hbA;   // alias: hbA dead after step2 batch

    prep_kernel<<<21, 256, 0, stream>>>(W_ih, W_hh, b_ih, b_hh, addr_emb,
                                        pid_emb, sid_emb, mlp_w2, mlp_w3,
                                        conv1_w, conv1_b, conv2_w,
                                        Wb, Wobs_b, WsampT, bias_all, pid_rows,
                                        sid_rows, w2t, w3t, w1p, Btg);
    conv_kernel<<<BATCH, 256, 0, stream>>>(obs, w1p, Btg, conv2_b, obs_emb_b);
    obs_gemm<<<512, 512, 0, stream>>>(obs_emb_b, Wobs_b, obs_part);

    // step0: h=c=0 -> hb0, c0
    step0_ew<<<BATCH, 256, 0, stream>>>(obs_part, bias_all + 0 * 1024, c0, hb0);

    // step1+step1b merged (same GEMM on h0, pid samp): biases 1 & 3.
    // outputs: (hbA,cA) branch-a, (hbD,cB) branch-b. head pid(3) on h0 -> 0..2
    lstm_mfma<1, 3, 1, true><<<512, 512, 0, stream>>>(
        hb0, nullptr, c0, nullptr, hbA, nullptr, cA, nullptr, hbD, cB,
        obs_part, bias_all + 1 * 1024, nullptr, bias_all + 3 * 1024,
        pid_rows, program_id, nullptr, nullptr, nullptr, Wb,
        pid_ext_w, pid_ext_b, out, 0, 0);

    // step2 (sub0: hbA,cA -> hbB, cA; sid[shape_id]; head sid on h1 -> 3..4)
    // step2b(sub1: hbD,cB -> hbE, cB; sid[shape_id_0]; head sid0 on h1b -> 7..8)
    lstm_mfma<1, 2, 2, false><<<1024, 512, 0, stream>>>(
        hbA, hbD, cA, cB, hbB, hbE, cA, cB, nullptr, nullptr,
        obs_part, bias_all + 2 * 1024, bias_all + 4 * 1024, nullptr,
        sid_rows, shape_id, shape_id_0, nullptr, nullptr, Wb,
        sid_ext_w, sid_ext_b, out, 3, 7);

    // rp_b0 head on h2 (hbB) -> 5..6
    rp_head<<<64, 256, 0, stream>>>(hbB, rp_ext_w, rp_ext_b, eps_rp, out, 5, nullptr);

    // step3b: hbE,cB -> hbC,cB; sid[shape_id_1]; head sid1 on h2b -> 9..10
    lstm_mfma<1, 2, 1, false><<<512, 512, 0, stream>>>(
        hbE, nullptr, cB, nullptr, hbC, nullptr, cB, nullptr, nullptr, nullptr,
        obs_part, bias_all + 5 * 1024, nullptr, nullptr,
        sid_rows, shape_id_1, nullptr, nullptr, nullptr, Wb,
        sid_ext_w, sid_ext_b, out, 9, 0);

    // rp0 head on h3b (hbC) -> 11..12 (+store)
    rp_head<<<64, 256, 0, stream>>>(hbC, rp_ext_w, rp_ext_b, eps_rp0, out, 11, rp0);
    mlp_kernel<<<BATCH, 128, 0, stream>>>(rp0, mlp_w1, mlp_b1, w2t, mlp_b2,
                                          w3t, mlp_b3, rp0_emb);

    // step4b: hbC,cB -> hbF,cB; samp = rp0_emb @ WsampT; no head
    lstm_mfma<2, 0, 1, false><<<512, 512, 0, stream>>>(
        hbC, nullptr, cB, nullptr, hbF, nullptr, cB, nullptr, nullptr, nullptr,
        obs_part, bias_all + 6 * 1024, nullptr, nullptr,
        nullptr, nullptr, nullptr, rp0_emb, WsampT, Wb,
        nullptr, nullptr, out, 0, 0);

    // rp1 head on h4b (hbF) -> 13..14
    rp_head<<<64, 256, 0, stream>>>(hbF, rp_ext_w, rp_ext_b, eps_rp1, out, 13, nullptr);
}